// Round 5
// baseline (668.451 us; speedup 1.0000x reference)
//
#include <hip/hip_runtime.h>
#include <hip/hip_bf16.h>
#include <type_traits>

using bf16 = __hip_bfloat16;

typedef __bf16 bf16x8 __attribute__((ext_vector_type(8)));
typedef unsigned short u16x8 __attribute__((ext_vector_type(8)));
typedef float f32x4 __attribute__((ext_vector_type(4)));

constexpr int Bdim = 8, Sdim = 2048, Idim = 1024, Hdim = 4096, Odim = 1024;
constexpr int CH = 64;              // scan chunks per sequence
constexpr int CL = Sdim / CH;       // 32 steps per chunk

#define EP_SIGMOID 0
#define EP_RELU    1
#define EP_BIAS    2

__device__ __forceinline__ void async16(void* lds, const void* g) {
    __builtin_amdgcn_global_load_lds(
        (const __attribute__((address_space(1))) unsigned int*)g,
        (__attribute__((address_space(3))) unsigned int*)lds,
        16, 0, 0);
}

// f32 -> bf16 convert; n multiple of 1024; 4 elems/thread
__global__ __launch_bounds__(256) void cvt_f32_bf16(const float* __restrict__ in,
                                                    bf16* __restrict__ out, int n) {
    const int i = (blockIdx.x * 256 + threadIdx.x) * 4;
    if (i >= n) return;
    const float4 v = *(const float4*)(in + i);
    union { unsigned short us[4]; unsigned long long u64; } r;
    r.us[0] = __bfloat16_as_ushort(__float2bfloat16(v.x));
    r.us[1] = __bfloat16_as_ushort(__float2bfloat16(v.y));
    r.us[2] = __bfloat16_as_ushort(__float2bfloat16(v.z));
    r.us[3] = __bfloat16_as_ushort(__float2bfloat16(v.w));
    *(unsigned long long*)(out + i) = r.u64;
}

// load 8 consecutive elements as bf16 (f32 converted in-register)
__device__ __forceinline__ u16x8 load8(const float* p) {
    const float4 v0 = *(const float4*)p;
    const float4 v1 = *(const float4*)(p + 4);
    u16x8 r;
    r[0] = __bfloat16_as_ushort(__float2bfloat16(v0.x));
    r[1] = __bfloat16_as_ushort(__float2bfloat16(v0.y));
    r[2] = __bfloat16_as_ushort(__float2bfloat16(v0.z));
    r[3] = __bfloat16_as_ushort(__float2bfloat16(v0.w));
    r[4] = __bfloat16_as_ushort(__float2bfloat16(v1.x));
    r[5] = __bfloat16_as_ushort(__float2bfloat16(v1.y));
    r[6] = __bfloat16_as_ushort(__float2bfloat16(v1.z));
    r[7] = __bfloat16_as_ushort(__float2bfloat16(v1.w));
    return r;
}
__device__ __forceinline__ u16x8 load8(const bf16* p) { return *(const u16x8*)p; }

// C[m,n] = sum_k A[m,k]*B[n,k] (B row-major [N,K] == B^T). f32 bias.
// Output dtype TO (bf16 or float). 128x128 tile, BK=32, 256 thr, 2x2 waves.
template <int MODE, typename TA, typename TB, typename TO>
__global__ __launch_bounds__(256) void gemm_bt(const TA* __restrict__ A,
                                               const TB* __restrict__ Bm,
                                               const float* __restrict__ bias,
                                               TO* __restrict__ outp,
                                               int N, int K) {
    __shared__ __align__(16) unsigned short Alds[128 * 32];
    __shared__ __align__(16) unsigned short Blds[128 * 32];

    const int tid  = threadIdx.x;
    const int lane = tid & 63;
    const int wave = tid >> 6;
    const int wr = wave >> 1, wc = wave & 1;
    const int quad = lane >> 4, l15 = lane & 15;

    const int m0 = blockIdx.y * 128;
    const int n0 = blockIdx.x * 128;

    // staging: thread t covers (row = t>>2 [+64], k-chunk = (t&3)*8)
    const int srow = tid >> 2;
    const int scol = (tid & 3) * 8;
    const TA* ag0 = A  + (size_t)(m0 + srow) * K + scol;
    const TA* ag1 = ag0 + (size_t)64 * K;
    const TB* bg0 = Bm + (size_t)(n0 + srow) * K + scol;
    const TB* bg1 = bg0 + (size_t)64 * K;
    unsigned short* al0 = Alds + tid * 8;
    unsigned short* al1 = al0 + 2048;
    unsigned short* bl0 = Blds + tid * 8;
    unsigned short* bl1 = bl0 + 2048;

    f32x4 acc[4][4];
#pragma unroll
    for (int i = 0; i < 4; ++i)
#pragma unroll
        for (int j = 0; j < 4; ++j) acc[i][j] = {0.f, 0.f, 0.f, 0.f};

    constexpr bool FAST = std::is_same_v<TA, bf16> && std::is_same_v<TB, bf16>;

    for (int k0 = 0; k0 < K; k0 += 32) {
        if constexpr (FAST) {
            async16(al0, ag0); async16(al1, ag1);
            async16(bl0, bg0); async16(bl1, bg1);
        } else {
            const u16x8 a0 = load8(ag0), a1 = load8(ag1);
            const u16x8 b0 = load8(bg0), b1 = load8(bg1);
            *(u16x8*)al0 = a0; *(u16x8*)al1 = a1;
            *(u16x8*)bl0 = b0; *(u16x8*)bl1 = b1;
        }
        ag0 += 32; ag1 += 32; bg0 += 32; bg1 += 32;
        __syncthreads();   // tiles ready (drains vmcnt for async path)

        bf16x8 af[4], bfv[4];
#pragma unroll
        for (int mi = 0; mi < 4; ++mi) {
            const u16x8 t = *(const u16x8*)(Alds + (wr * 64 + mi * 16 + l15) * 32 + quad * 8);
            af[mi] = __builtin_bit_cast(bf16x8, t);
        }
#pragma unroll
        for (int ni = 0; ni < 4; ++ni) {
            const u16x8 t = *(const u16x8*)(Blds + (wc * 64 + ni * 16 + l15) * 32 + quad * 8);
            bfv[ni] = __builtin_bit_cast(bf16x8, t);
        }
#pragma unroll
        for (int mi = 0; mi < 4; ++mi)
#pragma unroll
            for (int ni = 0; ni < 4; ++ni)
                acc[mi][ni] = __builtin_amdgcn_mfma_f32_16x16x32_bf16(af[mi], bfv[ni], acc[mi][ni], 0, 0, 0);
        __syncthreads();   // protect LDS for next stage
    }

    // D: row = quad*4 + reg, col = l15 (verified m89/m91 mapping)
#pragma unroll
    for (int ni = 0; ni < 4; ++ni) {
        const int ncol = n0 + wc * 64 + ni * 16 + l15;
        const float bv = bias[ncol];
#pragma unroll
        for (int mi = 0; mi < 4; ++mi) {
            const int mrow = m0 + wr * 64 + mi * 16 + quad * 4;
#pragma unroll
            for (int r = 0; r < 4; ++r) {
                float v = acc[mi][ni][r] + bv;
                if constexpr (MODE == EP_SIGMOID) v = 1.f / (1.f + __expf(-v));
                if constexpr (MODE == EP_RELU)    v = v > 0.f ? v : 0.f;
                if constexpr (std::is_same_v<TO, bf16>)
                    outp[(size_t)(mrow + r) * N + ncol] = __float2bfloat16(v);
                else
                    outp[(size_t)(mrow + r) * N + ncol] = v;
            }
        }
    }
}

// phase 1: per-chunk affine coefficients  buf_out = P*buf_in + Q
__global__ __launch_bounds__(256) void scan_p1(const float* __restrict__ x,
                                               const bf16* __restrict__ decay,
                                               float* __restrict__ P,
                                               float* __restrict__ Q) {
    const int tid = threadIdx.x;
    const int blk = blockIdx.x;          // (b*CH + c)*4 + itile
    const int itile = blk & 3;
    const int bc = blk >> 2;
    const int c = bc & (CH - 1);
    const int b = bc >> 6;
    const int i = itile * 256 + tid;
    size_t idx = ((size_t)(b * Sdim + c * CL)) * Idim + i;
    float p = 1.f, q = 0.f;
#pragma unroll 4
    for (int j = 0; j < CL; ++j) {
        const float d = __bfloat162float(decay[idx]);
        const float xx = x[idx];
        q = q * d + (1.f - d) * xx;
        p *= d;
        idx += Idim;
    }
    P[(size_t)bc * Idim + i] = p;
    Q[(size_t)bc * Idim + i] = q;
}

// phase 2: sequential combine across chunks (tiny)
__global__ __launch_bounds__(256) void scan_p2(const float* __restrict__ P,
                                               const float* __restrict__ Q,
                                               float* __restrict__ buf0,
                                               int G) {
    const int g = blockIdx.x * 256 + threadIdx.x;
    const int b = g >> 10;
    const int i = g & (Idim - 1);
    if (b >= G) return;
    float buf = 0.f;
    for (int c = 0; c < CH; ++c) {
        const size_t o = ((size_t)(b * CH + c)) * Idim + i;
        buf0[o] = buf;
        buf = P[o] * buf + Q[o];
    }
}

// phase 3: replay with correct init, write combined = x*d + buf (bf16)
__global__ __launch_bounds__(256) void scan_p3(const float* __restrict__ x,
                                               const bf16* __restrict__ decay,
                                               const float* __restrict__ buf0,
                                               bf16* __restrict__ comb) {
    const int tid = threadIdx.x;
    const int blk = blockIdx.x;
    const int itile = blk & 3;
    const int bc = blk >> 2;
    const int c = bc & (CH - 1);
    const int b = bc >> 6;
    const int i = itile * 256 + tid;
    size_t idx = ((size_t)(b * Sdim + c * CL)) * Idim + i;
    float buf = buf0[(size_t)bc * Idim + i];
#pragma unroll 4
    for (int j = 0; j < CL; ++j) {
        const float d = __bfloat162float(decay[idx]);
        const float xx = x[idx];
        buf = buf * d + (1.f - d) * xx;
        comb[idx] = __float2bfloat16(xx * d + buf);
        idx += Idim;
    }
}

extern "C" void kernel_launch(void* const* d_in, const int* in_sizes, int n_in,
                              void* d_out, int out_size, void* d_ws, size_t ws_size,
                              hipStream_t stream) {
    const float* x  = (const float*)d_in[0];
    const float* W1 = (const float*)d_in[1];
    const float* b1 = (const float*)d_in[2];
    const float* W2 = (const float*)d_in[3];
    const float* b2 = (const float*)d_in[4];
    const float* Wg = (const float*)d_in[5];
    const float* bg = (const float*)d_in[6];
    float* out = (float*)d_out;                       // OUTPUT IS F32

    const dim3 blk(256);

    const size_t nW1 = (size_t)Hdim * Idim;           // 4.19M
    const size_t nW2 = (size_t)Odim * Hdim;           // 4.19M
    const size_t nWg = (size_t)Idim * Idim;           // 1.05M
    const size_t wCopies = (nW1 + nW2 + nWg) * 2;     // 18.9 MB

    const size_t xbB   = (size_t)Sdim * Idim * 2;     // per-batch bf16 x: 4 MB
    const size_t dB    = xbB;                         // decay: 4 MB
    const size_t cmbB  = xbB;                         // comb: 4 MB
    const size_t pB    = (size_t)CH * Idim * 4;       // 256 KB
    const size_t perBatch = xbB + dB + cmbB + 3 * pB; // 12.75 MB

    int G = 0;                                         // 0 = fallback mode
    if (ws_size >= wCopies + 8 * perBatch) G = 8;
    else if (ws_size >= wCopies + 4 * perBatch) G = 4;
    else if (ws_size >= wCopies + 2 * perBatch) G = 2;
    else if (ws_size >= wCopies + 1 * perBatch) G = 1;

    if (G > 0) {
        // ---------- fast path: bf16 copies + async16 GEMMs ----------
        char* p = (char*)d_ws;
        bf16* W1b = (bf16*)p;  p += nW1 * 2;
        bf16* W2b = (bf16*)p;  p += nW2 * 2;
        bf16* Wgb = (bf16*)p;  p += nWg * 2;
        bf16*  xb   = (bf16*)p;
        bf16*  decay= (bf16*)(p + (size_t)G * xbB);
        bf16*  comb = (bf16*)(p + (size_t)G * (xbB + dB));
        float* P    = (float*)(p + (size_t)G * (xbB + dB + cmbB));
        float* Q    = (float*)(p + (size_t)G * (xbB + dB + cmbB + pB));
        float* buf0 = (float*)(p + (size_t)G * (xbB + dB + cmbB + 2 * pB));
        bf16*  hid  = xb;                 // reuses xb+decay (G*8MB) after scan
        const int chunk_rows = G * 1024;  // hid = chunk_rows*Hdim*2 = G*8MB

        cvt_f32_bf16<<<(int)(nW1 / 1024), blk, 0, stream>>>(W1, W1b, (int)nW1);
        cvt_f32_bf16<<<(int)(nW2 / 1024), blk, 0, stream>>>(W2, W2b, (int)nW2);
        cvt_f32_bf16<<<(int)(nWg / 1024), blk, 0, stream>>>(Wg, Wgb, (int)nWg);

        for (int b0 = 0; b0 < Bdim; b0 += G) {
            const float* xg = x + (size_t)b0 * Sdim * Idim;
            const int rowsG = G * Sdim;
            const int nXg = rowsG * Idim;

            cvt_f32_bf16<<<nXg / 1024, blk, 0, stream>>>(xg, xb, nXg);

            gemm_bt<EP_SIGMOID, bf16, bf16, bf16>
                <<<dim3(Idim / 128, rowsG / 128), blk, 0, stream>>>(
                    xb, Wgb, bg, decay, Idim, Idim);

            scan_p1<<<G * CH * (Idim / 256), blk, 0, stream>>>(xg, decay, P, Q);
            scan_p2<<<G * Idim / 256, blk, 0, stream>>>(P, Q, buf0, G);
            scan_p3<<<G * CH * (Idim / 256), blk, 0, stream>>>(xg, decay, buf0, comb);

            for (int r0 = 0; r0 < rowsG; r0 += chunk_rows) {
                const int rows = (rowsG - r0 < chunk_rows) ? rowsG - r0 : chunk_rows;
                gemm_bt<EP_RELU, bf16, bf16, bf16>
                    <<<dim3(Hdim / 128, rows / 128), blk, 0, stream>>>(
                        comb + (size_t)r0 * Idim, W1b, b1, hid, Hdim, Idim);
                gemm_bt<EP_BIAS, bf16, bf16, float>
                    <<<dim3(Odim / 128, rows / 128), blk, 0, stream>>>(
                        hid, W2b, b2, out + (size_t)(b0 * Sdim + r0) * Odim, Odim, Hdim);
            }
        }
    } else {
        // ---------- fallback: no copies, in-register f32->bf16 ----------
        char* p = (char*)d_ws;
        bf16*  decay= (bf16*)p;
        bf16*  comb = (bf16*)(p + dB);
        float* P    = (float*)(p + dB + cmbB);
        float* Q    = (float*)(p + dB + cmbB + pB);
        float* buf0 = (float*)(p + dB + cmbB + 2 * pB);
        char*  hp   = p + dB + cmbB + 3 * pB;
        size_t rem  = (ws_size > (size_t)(hp - (char*)d_ws))
                        ? ws_size - (size_t)(hp - (char*)d_ws) : 0;
        int chunk_rows = (int)((rem / ((size_t)Hdim * 2)) / 128) * 128;
        if (chunk_rows < 128) chunk_rows = 128;
        if (chunk_rows > Sdim) chunk_rows = Sdim;
        bf16* hid = (bf16*)hp;

        for (int b0 = 0; b0 < Bdim; ++b0) {
            const float* xg = x + (size_t)b0 * Sdim * Idim;

            gemm_bt<EP_SIGMOID, float, float, bf16>
                <<<dim3(Idim / 128, Sdim / 128), blk, 0, stream>>>(
                    xg, Wg, bg, decay, Idim, Idim);

            scan_p1<<<CH * (Idim / 256), blk, 0, stream>>>(xg, decay, P, Q);
            scan_p2<<<Idim / 256, blk, 0, stream>>>(P, Q, buf0, 1);
            scan_p3<<<CH * (Idim / 256), blk, 0, stream>>>(xg, decay, buf0, comb);

            for (int r0 = 0; r0 < Sdim; r0 += chunk_rows) {
                const int rows = (Sdim - r0 < chunk_rows) ? Sdim - r0 : chunk_rows;
                gemm_bt<EP_RELU, bf16, float, bf16>
                    <<<dim3(Hdim / 128, rows / 128), blk, 0, stream>>>(
                        comb + (size_t)r0 * Idim, W1, b1, hid, Hdim, Idim);
                gemm_bt<EP_BIAS, bf16, float, float>
                    <<<dim3(Odim / 128, rows / 128), blk, 0, stream>>>(
                        hid, W2, b2, out + (size_t)(b0 * Sdim + r0) * Odim, Odim, Hdim);
            }
        }
    }
}

// Round 6
// 628.030 us; speedup vs baseline: 1.0644x; 1.0644x over previous
//
#include <hip/hip_runtime.h>
#include <hip/hip_bf16.h>
#include <type_traits>

using bf16 = __hip_bfloat16;

typedef __bf16 bf16x8 __attribute__((ext_vector_type(8)));
typedef unsigned short u16x8 __attribute__((ext_vector_type(8)));
typedef float f32x4 __attribute__((ext_vector_type(4)));

constexpr int Bdim = 8, Sdim = 2048, Idim = 1024, Hdim = 4096, Odim = 1024;
constexpr int CH = 64;              // scan chunks per sequence
constexpr int CL = Sdim / CH;       // 32 steps per chunk

#define EP_SIGMOID 0
#define EP_RELU    1
#define EP_BIAS    2

__device__ __forceinline__ void async16(void* lds, const void* g) {
    __builtin_amdgcn_global_load_lds(
        (const __attribute__((address_space(1))) unsigned int*)g,
        (__attribute__((address_space(3))) unsigned int*)lds,
        16, 0, 0);
}

// f32 -> bf16 convert; n multiple of 1024; 4 elems/thread
__global__ __launch_bounds__(256) void cvt_f32_bf16(const float* __restrict__ in,
                                                    bf16* __restrict__ out, int n) {
    const int i = (blockIdx.x * 256 + threadIdx.x) * 4;
    if (i >= n) return;
    const float4 v = *(const float4*)(in + i);
    union { unsigned short us[4]; unsigned long long u64; } r;
    r.us[0] = __bfloat16_as_ushort(__float2bfloat16(v.x));
    r.us[1] = __bfloat16_as_ushort(__float2bfloat16(v.y));
    r.us[2] = __bfloat16_as_ushort(__float2bfloat16(v.z));
    r.us[3] = __bfloat16_as_ushort(__float2bfloat16(v.w));
    *(unsigned long long*)(out + i) = r.u64;
}

// load 8 consecutive elements as bf16 (f32 converted in-register)
__device__ __forceinline__ u16x8 load8(const float* p) {
    const float4 v0 = *(const float4*)p;
    const float4 v1 = *(const float4*)(p + 4);
    u16x8 r;
    r[0] = __bfloat16_as_ushort(__float2bfloat16(v0.x));
    r[1] = __bfloat16_as_ushort(__float2bfloat16(v0.y));
    r[2] = __bfloat16_as_ushort(__float2bfloat16(v0.z));
    r[3] = __bfloat16_as_ushort(__float2bfloat16(v0.w));
    r[4] = __bfloat16_as_ushort(__float2bfloat16(v1.x));
    r[5] = __bfloat16_as_ushort(__float2bfloat16(v1.y));
    r[6] = __bfloat16_as_ushort(__float2bfloat16(v1.z));
    r[7] = __bfloat16_as_ushort(__float2bfloat16(v1.w));
    return r;
}
__device__ __forceinline__ u16x8 load8(const bf16* p) { return *(const u16x8*)p; }

__device__ __forceinline__ float toF(float v) { return v; }
__device__ __forceinline__ float toF(bf16 v)  { return __bfloat162float(v); }

// C[m,n] = sum_k A[m,k]*B[n,k] (B row-major [N,K] == B^T). f32 bias.
// Output dtype TO. 128x128 tile, BK=32, 256 thr, 2x2 waves, 4x4 MFMA.
// 1-D grid of (M/128)*(N/128) blocks, group-swizzled (GROUP_M m-tiles share
// B-panel in L2; A-strips reused across the whole n sweep).
template <int MODE, typename TA, typename TB, typename TO>
__global__ __launch_bounds__(256) void gemm_bt(const TA* __restrict__ A,
                                               const TB* __restrict__ Bm,
                                               const float* __restrict__ bias,
                                               TO* __restrict__ outp,
                                               int N, int K) {
    __shared__ __align__(16) unsigned short Alds[128 * 32];
    __shared__ __align__(16) unsigned short Blds[128 * 32];

    const int tid  = threadIdx.x;
    const int lane = tid & 63;
    const int wave = tid >> 6;
    const int wr = wave >> 1, wc = wave & 1;
    const int quad = lane >> 4, l15 = lane & 15;

    // ---- group-swizzled block rasterization ----
    const int Nt = N >> 7;
    const int Mt = gridDim.x / Nt;
    constexpr int GRP = 8;
    const int gsz = GRP * Nt;
    const int g   = blockIdx.x / gsz;
    const int rem = blockIdx.x - g * gsz;
    const int mbase = g * GRP;
    int msz = Mt - mbase; if (msz > GRP) msz = GRP;
    const int m_idx = mbase + rem % msz;
    const int n_idx = rem / msz;
    const int m0 = m_idx * 128;
    const int n0 = n_idx * 128;

    // staging: thread t covers (row = t>>2 [+64], k-chunk = (t&3)*8)
    const int srow = tid >> 2;
    const int scol = (tid & 3) * 8;
    const TA* ag0 = A  + (size_t)(m0 + srow) * K + scol;
    const TA* ag1 = ag0 + (size_t)64 * K;
    const TB* bg0 = Bm + (size_t)(n0 + srow) * K + scol;
    const TB* bg1 = bg0 + (size_t)64 * K;
    unsigned short* al0 = Alds + tid * 8;
    unsigned short* al1 = al0 + 2048;
    unsigned short* bl0 = Blds + tid * 8;
    unsigned short* bl1 = bl0 + 2048;

    f32x4 acc[4][4];
#pragma unroll
    for (int i = 0; i < 4; ++i)
#pragma unroll
        for (int j = 0; j < 4; ++j) acc[i][j] = {0.f, 0.f, 0.f, 0.f};

    constexpr bool FAST = std::is_same_v<TA, bf16> && std::is_same_v<TB, bf16>;

    for (int k0 = 0; k0 < K; k0 += 32) {
        if constexpr (FAST) {
            async16(al0, ag0); async16(al1, ag1);
            async16(bl0, bg0); async16(bl1, bg1);
        } else {
            const u16x8 a0 = load8(ag0), a1 = load8(ag1);
            const u16x8 b0 = load8(bg0), b1 = load8(bg1);
            *(u16x8*)al0 = a0; *(u16x8*)al1 = a1;
            *(u16x8*)bl0 = b0; *(u16x8*)bl1 = b1;
        }
        ag0 += 32; ag1 += 32; bg0 += 32; bg1 += 32;
        __syncthreads();   // tiles ready (drains vmcnt for async path)

        bf16x8 af[4], bfv[4];
#pragma unroll
        for (int mi = 0; mi < 4; ++mi) {
            const u16x8 t = *(const u16x8*)(Alds + (wr * 64 + mi * 16 + l15) * 32 + quad * 8);
            af[mi] = __builtin_bit_cast(bf16x8, t);
        }
#pragma unroll
        for (int ni = 0; ni < 4; ++ni) {
            const u16x8 t = *(const u16x8*)(Blds + (wc * 64 + ni * 16 + l15) * 32 + quad * 8);
            bfv[ni] = __builtin_bit_cast(bf16x8, t);
        }
#pragma unroll
        for (int mi = 0; mi < 4; ++mi)
#pragma unroll
            for (int ni = 0; ni < 4; ++ni)
                acc[mi][ni] = __builtin_amdgcn_mfma_f32_16x16x32_bf16(af[mi], bfv[ni], acc[mi][ni], 0, 0, 0);
        __syncthreads();   // protect LDS for next stage
    }

    // D: row = quad*4 + reg, col = l15 (verified m89/m91 mapping)
#pragma unroll
    for (int ni = 0; ni < 4; ++ni) {
        const int ncol = n0 + wc * 64 + ni * 16 + l15;
        const float bv = bias[ncol];
#pragma unroll
        for (int mi = 0; mi < 4; ++mi) {
            const int mrow = m0 + wr * 64 + mi * 16 + quad * 4;
#pragma unroll
            for (int r = 0; r < 4; ++r) {
                float v = acc[mi][ni][r] + bv;
                if constexpr (MODE == EP_SIGMOID) v = 1.f / (1.f + __expf(-v));
                if constexpr (MODE == EP_RELU)    v = v > 0.f ? v : 0.f;
                if constexpr (std::is_same_v<TO, bf16>)
                    outp[(size_t)(mrow + r) * N + ncol] = __float2bfloat16(v);
                else
                    outp[(size_t)(mrow + r) * N + ncol] = v;
            }
        }
    }
}

// phase 1: per-chunk affine coefficients  buf_out = P*buf_in + Q
template <typename XT>
__global__ __launch_bounds__(256) void scan_p1(const XT* __restrict__ x,
                                               const bf16* __restrict__ decay,
                                               float* __restrict__ P,
                                               float* __restrict__ Q) {
    const int tid = threadIdx.x;
    const int blk = blockIdx.x;          // (b*CH + c)*4 + itile
    const int itile = blk & 3;
    const int bc = blk >> 2;
    const int c = bc & (CH - 1);
    const int b = bc >> 6;
    const int i = itile * 256 + tid;
    size_t idx = ((size_t)(b * Sdim + c * CL)) * Idim + i;
    float p = 1.f, q = 0.f;
#pragma unroll 4
    for (int j = 0; j < CL; ++j) {
        const float d = __bfloat162float(decay[idx]);
        const float xx = toF(x[idx]);
        q = q * d + (1.f - d) * xx;
        p *= d;
        idx += Idim;
    }
    P[(size_t)bc * Idim + i] = p;
    Q[(size_t)bc * Idim + i] = q;
}

// phase 2: sequential combine across chunks (tiny)
__global__ __launch_bounds__(256) void scan_p2(const float* __restrict__ P,
                                               const float* __restrict__ Q,
                                               float* __restrict__ buf0,
                                               int G) {
    const int g = blockIdx.x * 256 + threadIdx.x;
    const int b = g >> 10;
    const int i = g & (Idim - 1);
    if (b >= G) return;
    float buf = 0.f;
    for (int c = 0; c < CH; ++c) {
        const size_t o = ((size_t)(b * CH + c)) * Idim + i;
        buf0[o] = buf;
        buf = P[o] * buf + Q[o];
    }
}

// phase 3: replay with correct init, write combined = x*d + buf (bf16)
template <typename XT>
__global__ __launch_bounds__(256) void scan_p3(const XT* __restrict__ x,
                                               const bf16* __restrict__ decay,
                                               const float* __restrict__ buf0,
                                               bf16* __restrict__ comb) {
    const int tid = threadIdx.x;
    const int blk = blockIdx.x;
    const int itile = blk & 3;
    const int bc = blk >> 2;
    const int c = bc & (CH - 1);
    const int b = bc >> 6;
    const int i = itile * 256 + tid;
    size_t idx = ((size_t)(b * Sdim + c * CL)) * Idim + i;
    float buf = buf0[(size_t)bc * Idim + i];
#pragma unroll 4
    for (int j = 0; j < CL; ++j) {
        const float d = __bfloat162float(decay[idx]);
        const float xx = toF(x[idx]);
        buf = buf * d + (1.f - d) * xx;
        comb[idx] = __float2bfloat16(xx * d + buf);
        idx += Idim;
    }
}

extern "C" void kernel_launch(void* const* d_in, const int* in_sizes, int n_in,
                              void* d_out, int out_size, void* d_ws, size_t ws_size,
                              hipStream_t stream) {
    const float* x  = (const float*)d_in[0];
    const float* W1 = (const float*)d_in[1];
    const float* b1 = (const float*)d_in[2];
    const float* W2 = (const float*)d_in[3];
    const float* b2 = (const float*)d_in[4];
    const float* Wg = (const float*)d_in[5];
    const float* bg = (const float*)d_in[6];
    float* out = (float*)d_out;                       // output is f32

    const dim3 blk(256);

    const size_t nW1 = (size_t)Hdim * Idim;
    const size_t nW2 = (size_t)Odim * Hdim;
    const size_t nWg = (size_t)Idim * Idim;
    const size_t wCopies = (nW1 + nW2 + nWg) * 2;     // 18.9 MB

    const size_t xbB   = (size_t)Sdim * Idim * 2;     // per-batch bf16 x: 4 MB
    const size_t dB    = xbB;                         // decay: 4 MB
    const size_t cmbB  = xbB;                         // comb: 4 MB
    const size_t pB    = (size_t)CH * Idim * 4;       // 256 KB
    const size_t perBatch = xbB + dB + cmbB + 3 * pB; // 12.75 MB

    int G = 0;                                         // 0 = fallback mode
    if (ws_size >= wCopies + 8 * perBatch) G = 8;
    else if (ws_size >= wCopies + 4 * perBatch) G = 4;
    else if (ws_size >= wCopies + 2 * perBatch) G = 2;
    else if (ws_size >= wCopies + 1 * perBatch) G = 1;

    if (G > 0) {
        // ---------- fast path: bf16 copies + async16 GEMMs ----------
        char* p = (char*)d_ws;
        bf16* W1b = (bf16*)p;  p += nW1 * 2;
        bf16* W2b = (bf16*)p;  p += nW2 * 2;
        bf16* Wgb = (bf16*)p;  p += nWg * 2;
        bf16*  xb   = (bf16*)p;
        bf16*  decay= (bf16*)(p + (size_t)G * xbB);
        bf16*  comb = (bf16*)(p + (size_t)G * (xbB + dB));
        float* P    = (float*)(p + (size_t)G * (xbB + dB + cmbB));
        float* Q    = (float*)(p + (size_t)G * (xbB + dB + cmbB + pB));
        float* buf0 = (float*)(p + (size_t)G * (xbB + dB + cmbB + 2 * pB));
        bf16*  hid  = xb;                 // reuses xb+decay (G*8MB) after scan
        const int chunk_rows = G * 1024;  // hid = chunk_rows*Hdim*2 = G*8MB

        cvt_f32_bf16<<<(int)(nW1 / 1024), blk, 0, stream>>>(W1, W1b, (int)nW1);
        cvt_f32_bf16<<<(int)(nW2 / 1024), blk, 0, stream>>>(W2, W2b, (int)nW2);
        cvt_f32_bf16<<<(int)(nWg / 1024), blk, 0, stream>>>(Wg, Wgb, (int)nWg);

        for (int b0 = 0; b0 < Bdim; b0 += G) {
            const float* xg = x + (size_t)b0 * Sdim * Idim;
            const int rowsG = G * Sdim;
            const int nXg = rowsG * Idim;

            cvt_f32_bf16<<<nXg / 1024, blk, 0, stream>>>(xg, xb, nXg);

            gemm_bt<EP_SIGMOID, bf16, bf16, bf16>
                <<<(Idim / 128) * (rowsG / 128), blk, 0, stream>>>(
                    xb, Wgb, bg, decay, Idim, Idim);

            scan_p1<bf16><<<G * CH * (Idim / 256), blk, 0, stream>>>(xb, decay, P, Q);
            scan_p2<<<G * Idim / 256, blk, 0, stream>>>(P, Q, buf0, G);
            scan_p3<bf16><<<G * CH * (Idim / 256), blk, 0, stream>>>(xb, decay, buf0, comb);

            for (int r0 = 0; r0 < rowsG; r0 += chunk_rows) {
                const int rows = (rowsG - r0 < chunk_rows) ? rowsG - r0 : chunk_rows;
                gemm_bt<EP_RELU, bf16, bf16, bf16>
                    <<<(Hdim / 128) * (rows / 128), blk, 0, stream>>>(
                        comb + (size_t)r0 * Idim, W1b, b1, hid, Hdim, Idim);
                gemm_bt<EP_BIAS, bf16, bf16, float>
                    <<<(Odim / 128) * (rows / 128), blk, 0, stream>>>(
                        hid, W2b, b2, out + (size_t)(b0 * Sdim + r0) * Odim, Odim, Hdim);
            }
        }
    } else {
        // ---------- fallback: no copies, in-register f32->bf16 ----------
        char* p = (char*)d_ws;
        bf16*  decay= (bf16*)p;
        bf16*  comb = (bf16*)(p + dB);
        float* P    = (float*)(p + dB + cmbB);
        float* Q    = (float*)(p + dB + cmbB + pB);
        float* buf0 = (float*)(p + dB + cmbB + 2 * pB);
        char*  hp   = p + dB + cmbB + 3 * pB;
        size_t rem  = (ws_size > (size_t)(hp - (char*)d_ws))
                        ? ws_size - (size_t)(hp - (char*)d_ws) : 0;
        int chunk_rows = (int)((rem / ((size_t)Hdim * 2)) / 128) * 128;
        if (chunk_rows < 128) chunk_rows = 128;
        if (chunk_rows > Sdim) chunk_rows = Sdim;
        bf16* hid = (bf16*)hp;

        for (int b0 = 0; b0 < Bdim; ++b0) {
            const float* xg = x + (size_t)b0 * Sdim * Idim;

            gemm_bt<EP_SIGMOID, float, float, bf16>
                <<<(Idim / 128) * (Sdim / 128), blk, 0, stream>>>(
                    xg, Wg, bg, decay, Idim, Idim);

            scan_p1<float><<<CH * (Idim / 256), blk, 0, stream>>>(xg, decay, P, Q);
            scan_p2<<<Idim / 256, blk, 0, stream>>>(P, Q, buf0, 1);
            scan_p3<float><<<CH * (Idim / 256), blk, 0, stream>>>(xg, decay, buf0, comb);

            for (int r0 = 0; r0 < Sdim; r0 += chunk_rows) {
                const int rows = (Sdim - r0 < chunk_rows) ? Sdim - r0 : chunk_rows;
                gemm_bt<EP_RELU, bf16, float, bf16>
                    <<<(Hdim / 128) * (rows / 128), blk, 0, stream>>>(
                        comb + (size_t)r0 * Idim, W1, b1, hid, Hdim, Idim);
                gemm_bt<EP_BIAS, bf16, float, float>
                    <<<(Odim / 128) * (rows / 128), blk, 0, stream>>>(
                        hid, W2, b2, out + (size_t)(b0 * Sdim + r0) * Odim, Odim, Hdim);
            }
        }
    }
}

// Round 7
// 616.975 us; speedup vs baseline: 1.0834x; 1.0179x over previous
//
#include <hip/hip_runtime.h>
#include <hip/hip_bf16.h>
#include <type_traits>

using bf16 = __hip_bfloat16;

typedef __bf16 bf16x8 __attribute__((ext_vector_type(8)));
typedef unsigned short u16x8 __attribute__((ext_vector_type(8)));
typedef float f32x4 __attribute__((ext_vector_type(4)));

constexpr int Bdim = 8, Sdim = 2048, Idim = 1024, Hdim = 4096, Odim = 1024;
constexpr int CH = 64;              // scan chunks per sequence
constexpr int CL = Sdim / CH;       // 32 steps per chunk

#define EP_SIGMOID 0
#define EP_RELU    1
#define EP_BIAS    2

__device__ __forceinline__ void async16(void* lds, const void* g) {
    __builtin_amdgcn_global_load_lds(
        (const __attribute__((address_space(1))) unsigned int*)g,
        (__attribute__((address_space(3))) unsigned int*)lds,
        16, 0, 0);
}

// f32 -> bf16 convert; n multiple of 1024; 4 elems/thread
__global__ __launch_bounds__(256) void cvt_f32_bf16(const float* __restrict__ in,
                                                    bf16* __restrict__ out, int n) {
    const int i = (blockIdx.x * 256 + threadIdx.x) * 4;
    if (i >= n) return;
    const float4 v = *(const float4*)(in + i);
    union { unsigned short us[4]; unsigned long long u64; } r;
    r.us[0] = __bfloat16_as_ushort(__float2bfloat16(v.x));
    r.us[1] = __bfloat16_as_ushort(__float2bfloat16(v.y));
    r.us[2] = __bfloat16_as_ushort(__float2bfloat16(v.z));
    r.us[3] = __bfloat16_as_ushort(__float2bfloat16(v.w));
    *(unsigned long long*)(out + i) = r.u64;
}

// load 8 consecutive elements as bf16 (f32 converted in-register)
__device__ __forceinline__ u16x8 load8(const float* p) {
    const float4 v0 = *(const float4*)p;
    const float4 v1 = *(const float4*)(p + 4);
    u16x8 r;
    r[0] = __bfloat16_as_ushort(__float2bfloat16(v0.x));
    r[1] = __bfloat16_as_ushort(__float2bfloat16(v0.y));
    r[2] = __bfloat16_as_ushort(__float2bfloat16(v0.z));
    r[3] = __bfloat16_as_ushort(__float2bfloat16(v0.w));
    r[4] = __bfloat16_as_ushort(__float2bfloat16(v1.x));
    r[5] = __bfloat16_as_ushort(__float2bfloat16(v1.y));
    r[6] = __bfloat16_as_ushort(__float2bfloat16(v1.z));
    r[7] = __bfloat16_as_ushort(__float2bfloat16(v1.w));
    return r;
}
__device__ __forceinline__ u16x8 load8(const bf16* p) { return *(const u16x8*)p; }

__device__ __forceinline__ float toF(float v) { return v; }
__device__ __forceinline__ float toF(bf16 v)  { return __bfloat162float(v); }

// C[m,n] = sum_k A[m,k]*B[n,k] (B row-major [N,K] == B^T). f32 bias.
// Compile-time N,K. 128x128 tile, BK=32, 256 thr, 2x2 waves, 4x4 MFMA.
// XCD-aware 1-D grid: xcd = blk&7 owns n-strip [xcd*Nt/8, (xcd+1)*Nt/8);
// within an XCD, n fastest -> per-XCD L2 working set = B-strip + A-strip.
template <int MODE, int N, int K, typename TA, typename TB, typename TO>
__global__ __launch_bounds__(256) void gemm_bt(const TA* __restrict__ A,
                                               const TB* __restrict__ Bm,
                                               const float* __restrict__ bias,
                                               TO* __restrict__ outp) {
    __shared__ __align__(16) unsigned short Alds[128 * 32];
    __shared__ __align__(16) unsigned short Blds[128 * 32];

    const int tid  = threadIdx.x;
    const int lane = tid & 63;
    const int wave = tid >> 6;
    const int wr = wave >> 1, wc = wave & 1;
    const int quad = lane >> 4, l15 = lane & 15;

    // ---- XCD-aware rasterization (grid divisible by 8 by construction) ----
    constexpr int Nt = N >> 7;          // n-tiles (8 or 32)
    constexpr int NS = Nt >> 3;         // n-strip width per XCD (1 or 4)
    const int xcd = blockIdx.x & 7;
    const int idx = blockIdx.x >> 3;
    const int m_idx = idx / NS;         // constexpr divisor -> shift
    const int n_idx = xcd * NS + (idx % NS);
    const int m0 = m_idx * 128;
    const int n0 = n_idx * 128;

    // staging: thread t covers (row = t>>2 [+64], k-chunk = (t&3)*8)
    const int srow = tid >> 2;
    const int scol = (tid & 3) * 8;
    const TA* ag0 = A  + (size_t)(m0 + srow) * K + scol;
    const TA* ag1 = ag0 + (size_t)64 * K;
    const TB* bg0 = Bm + (size_t)(n0 + srow) * K + scol;
    const TB* bg1 = bg0 + (size_t)64 * K;
    unsigned short* al0 = Alds + tid * 8;
    unsigned short* al1 = al0 + 2048;
    unsigned short* bl0 = Blds + tid * 8;
    unsigned short* bl1 = bl0 + 2048;

    f32x4 acc[4][4];
#pragma unroll
    for (int i = 0; i < 4; ++i)
#pragma unroll
        for (int j = 0; j < 4; ++j) acc[i][j] = {0.f, 0.f, 0.f, 0.f};

    constexpr bool FAST = std::is_same_v<TA, bf16> && std::is_same_v<TB, bf16>;

#pragma unroll 8
    for (int k0 = 0; k0 < K; k0 += 32) {
        if constexpr (FAST) {
            async16(al0, ag0); async16(al1, ag1);
            async16(bl0, bg0); async16(bl1, bg1);
        } else {
            const u16x8 a0 = load8(ag0), a1 = load8(ag1);
            const u16x8 b0 = load8(bg0), b1 = load8(bg1);
            *(u16x8*)al0 = a0; *(u16x8*)al1 = a1;
            *(u16x8*)bl0 = b0; *(u16x8*)bl1 = b1;
        }
        ag0 += 32; ag1 += 32; bg0 += 32; bg1 += 32;
        __syncthreads();   // tiles ready (drains vmcnt for async path)

        bf16x8 af[4], bfv[4];
#pragma unroll
        for (int mi = 0; mi < 4; ++mi) {
            const u16x8 t = *(const u16x8*)(Alds + (wr * 64 + mi * 16 + l15) * 32 + quad * 8);
            af[mi] = __builtin_bit_cast(bf16x8, t);
        }
#pragma unroll
        for (int ni = 0; ni < 4; ++ni) {
            const u16x8 t = *(const u16x8*)(Blds + (wc * 64 + ni * 16 + l15) * 32 + quad * 8);
            bfv[ni] = __builtin_bit_cast(bf16x8, t);
        }
#pragma unroll
        for (int mi = 0; mi < 4; ++mi)
#pragma unroll
            for (int ni = 0; ni < 4; ++ni)
                acc[mi][ni] = __builtin_amdgcn_mfma_f32_16x16x32_bf16(af[mi], bfv[ni], acc[mi][ni], 0, 0, 0);
        __syncthreads();   // protect LDS for next stage
    }

    // D: row = quad*4 + reg, col = l15 (verified m89/m91 mapping)
#pragma unroll
    for (int ni = 0; ni < 4; ++ni) {
        const int ncol = n0 + wc * 64 + ni * 16 + l15;
        const float bv = bias[ncol];
#pragma unroll
        for (int mi = 0; mi < 4; ++mi) {
            const int mrow = m0 + wr * 64 + mi * 16 + quad * 4;
#pragma unroll
            for (int r = 0; r < 4; ++r) {
                float v = acc[mi][ni][r] + bv;
                if constexpr (MODE == EP_SIGMOID) v = 1.f / (1.f + __expf(-v));
                if constexpr (MODE == EP_RELU)    v = v > 0.f ? v : 0.f;
                if constexpr (std::is_same_v<TO, bf16>)
                    outp[(size_t)(mrow + r) * N + ncol] = __float2bfloat16(v);
                else
                    outp[(size_t)(mrow + r) * N + ncol] = v;
            }
        }
    }
}

// phase 1: per-chunk affine coefficients  buf_out = P*buf_in + Q
template <typename XT>
__global__ __launch_bounds__(256) void scan_p1(const XT* __restrict__ x,
                                               const bf16* __restrict__ decay,
                                               float* __restrict__ P,
                                               float* __restrict__ Q) {
    const int tid = threadIdx.x;
    const int blk = blockIdx.x;          // (b*CH + c)*4 + itile
    const int itile = blk & 3;
    const int bc = blk >> 2;
    const int c = bc & (CH - 1);
    const int b = bc >> 6;
    const int i = itile * 256 + tid;
    size_t idx = ((size_t)(b * Sdim + c * CL)) * Idim + i;
    float p = 1.f, q = 0.f;
#pragma unroll 4
    for (int j = 0; j < CL; ++j) {
        const float d = __bfloat162float(decay[idx]);
        const float xx = toF(x[idx]);
        q = q * d + (1.f - d) * xx;
        p *= d;
        idx += Idim;
    }
    P[(size_t)bc * Idim + i] = p;
    Q[(size_t)bc * Idim + i] = q;
}

// phase 2: sequential combine across chunks (tiny)
__global__ __launch_bounds__(256) void scan_p2(const float* __restrict__ P,
                                               const float* __restrict__ Q,
                                               float* __restrict__ buf0,
                                               int G) {
    const int g = blockIdx.x * 256 + threadIdx.x;
    const int b = g >> 10;
    const int i = g & (Idim - 1);
    if (b >= G) return;
    float buf = 0.f;
    for (int c = 0; c < CH; ++c) {
        const size_t o = ((size_t)(b * CH + c)) * Idim + i;
        buf0[o] = buf;
        buf = P[o] * buf + Q[o];
    }
}

// phase 3: replay with correct init, write combined = x*d + buf (bf16)
template <typename XT>
__global__ __launch_bounds__(256) void scan_p3(const XT* __restrict__ x,
                                               const bf16* __restrict__ decay,
                                               const float* __restrict__ buf0,
                                               bf16* __restrict__ comb) {
    const int tid = threadIdx.x;
    const int blk = blockIdx.x;
    const int itile = blk & 3;
    const int bc = blk >> 2;
    const int c = bc & (CH - 1);
    const int b = bc >> 6;
    const int i = itile * 256 + tid;
    size_t idx = ((size_t)(b * Sdim + c * CL)) * Idim + i;
    float buf = buf0[(size_t)bc * Idim + i];
#pragma unroll 4
    for (int j = 0; j < CL; ++j) {
        const float d = __bfloat162float(decay[idx]);
        const float xx = toF(x[idx]);
        buf = buf * d + (1.f - d) * xx;
        comb[idx] = __float2bfloat16(xx * d + buf);
        idx += Idim;
    }
}

extern "C" void kernel_launch(void* const* d_in, const int* in_sizes, int n_in,
                              void* d_out, int out_size, void* d_ws, size_t ws_size,
                              hipStream_t stream) {
    const float* x  = (const float*)d_in[0];
    const float* W1 = (const float*)d_in[1];
    const float* b1 = (const float*)d_in[2];
    const float* W2 = (const float*)d_in[3];
    const float* b2 = (const float*)d_in[4];
    const float* Wg = (const float*)d_in[5];
    const float* bg = (const float*)d_in[6];
    float* out = (float*)d_out;                       // output is f32

    const dim3 blk(256);

    const size_t nW1 = (size_t)Hdim * Idim;
    const size_t nW2 = (size_t)Odim * Hdim;
    const size_t nWg = (size_t)Idim * Idim;
    const size_t wCopies = (nW1 + nW2 + nWg) * 2;     // 18.9 MB

    const size_t xbB   = (size_t)Sdim * Idim * 2;     // per-batch bf16 x: 4 MB
    const size_t dB    = xbB;                         // decay: 4 MB
    const size_t cmbB  = xbB;                         // comb: 4 MB
    const size_t pB    = (size_t)CH * Idim * 4;       // 256 KB
    const size_t perBatch = xbB + dB + cmbB + 3 * pB; // 12.75 MB

    int G = 0;                                         // 0 = fallback mode
    if (ws_size >= wCopies + 8 * perBatch) G = 8;
    else if (ws_size >= wCopies + 4 * perBatch) G = 4;
    else if (ws_size >= wCopies + 2 * perBatch) G = 2;
    else if (ws_size >= wCopies + 1 * perBatch) G = 1;

    if (G > 0) {
        // ---------- fast path: bf16 copies + async16 GEMMs ----------
        char* p = (char*)d_ws;
        bf16* W1b = (bf16*)p;  p += nW1 * 2;
        bf16* W2b = (bf16*)p;  p += nW2 * 2;
        bf16* Wgb = (bf16*)p;  p += nWg * 2;
        bf16*  xb   = (bf16*)p;
        bf16*  decay= (bf16*)(p + (size_t)G * xbB);
        bf16*  comb = (bf16*)(p + (size_t)G * (xbB + dB));
        float* P    = (float*)(p + (size_t)G * (xbB + dB + cmbB));
        float* Q    = (float*)(p + (size_t)G * (xbB + dB + cmbB + pB));
        float* buf0 = (float*)(p + (size_t)G * (xbB + dB + cmbB + 2 * pB));
        bf16*  hid  = xb;                 // reuses xb+decay (G*8MB) after scan
        const int chunk_rows = G * 1024;  // hid = chunk_rows*Hdim*2 = G*8MB

        cvt_f32_bf16<<<(int)(nW1 / 1024), blk, 0, stream>>>(W1, W1b, (int)nW1);
        cvt_f32_bf16<<<(int)(nW2 / 1024), blk, 0, stream>>>(W2, W2b, (int)nW2);
        cvt_f32_bf16<<<(int)(nWg / 1024), blk, 0, stream>>>(Wg, Wgb, (int)nWg);

        for (int b0 = 0; b0 < Bdim; b0 += G) {
            const float* xg = x + (size_t)b0 * Sdim * Idim;
            const int rowsG = G * Sdim;
            const int nXg = rowsG * Idim;

            cvt_f32_bf16<<<nXg / 1024, blk, 0, stream>>>(xg, xb, nXg);

            gemm_bt<EP_SIGMOID, Idim, Idim, bf16, bf16, bf16>
                <<<(Idim / 128) * (rowsG / 128), blk, 0, stream>>>(
                    xb, Wgb, bg, decay);

            scan_p1<bf16><<<G * CH * (Idim / 256), blk, 0, stream>>>(xb, decay, P, Q);
            scan_p2<<<G * Idim / 256, blk, 0, stream>>>(P, Q, buf0, G);
            scan_p3<bf16><<<G * CH * (Idim / 256), blk, 0, stream>>>(xb, decay, buf0, comb);

            for (int r0 = 0; r0 < rowsG; r0 += chunk_rows) {
                const int rows = (rowsG - r0 < chunk_rows) ? rowsG - r0 : chunk_rows;
                gemm_bt<EP_RELU, Hdim, Idim, bf16, bf16, bf16>
                    <<<(Hdim / 128) * (rows / 128), blk, 0, stream>>>(
                        comb + (size_t)r0 * Idim, W1b, b1, hid);
                gemm_bt<EP_BIAS, Odim, Hdim, bf16, bf16, float>
                    <<<(Odim / 128) * (rows / 128), blk, 0, stream>>>(
                        hid, W2b, b2, out + (size_t)(b0 * Sdim + r0) * Odim);
            }
        }
    } else {
        // ---------- fallback: no copies, in-register f32->bf16 ----------
        char* p = (char*)d_ws;
        bf16*  decay= (bf16*)p;
        bf16*  comb = (bf16*)(p + dB);
        float* P    = (float*)(p + dB + cmbB);
        float* Q    = (float*)(p + dB + cmbB + pB);
        float* buf0 = (float*)(p + dB + cmbB + 2 * pB);
        char*  hp   = p + dB + cmbB + 3 * pB;
        size_t rem  = (ws_size > (size_t)(hp - (char*)d_ws))
                        ? ws_size - (size_t)(hp - (char*)d_ws) : 0;
        int chunk_rows = (int)((rem / ((size_t)Hdim * 2)) / 128) * 128;
        if (chunk_rows < 128) chunk_rows = 128;
        if (chunk_rows > Sdim) chunk_rows = Sdim;
        bf16* hid = (bf16*)hp;

        for (int b0 = 0; b0 < Bdim; ++b0) {
            const float* xg = x + (size_t)b0 * Sdim * Idim;

            gemm_bt<EP_SIGMOID, Idim, Idim, float, float, bf16>
                <<<(Idim / 128) * (Sdim / 128), blk, 0, stream>>>(
                    xg, Wg, bg, decay);

            scan_p1<float><<<CH * (Idim / 256), blk, 0, stream>>>(xg, decay, P, Q);
            scan_p2<<<Idim / 256, blk, 0, stream>>>(P, Q, buf0, 1);
            scan_p3<float><<<CH * (Idim / 256), blk, 0, stream>>>(xg, decay, buf0, comb);

            for (int r0 = 0; r0 < Sdim; r0 += chunk_rows) {
                const int rows = (Sdim - r0 < chunk_rows) ? Sdim - r0 : chunk_rows;
                gemm_bt<EP_RELU, Hdim, Idim, bf16, float, bf16>
                    <<<(Hdim / 128) * (rows / 128), blk, 0, stream>>>(
                        comb + (size_t)r0 * Idim, W1, b1, hid);
                gemm_bt<EP_BIAS, Odim, Hdim, bf16, float, float>
                    <<<(Odim / 128) * (rows / 128), blk, 0, stream>>>(
                        hid, W2, b2, out + (size_t)(b0 * Sdim + r0) * Odim);
            }
        }
    }
}

// Round 8
// 572.862 us; speedup vs baseline: 1.1669x; 1.0770x over previous
//
#include <hip/hip_runtime.h>
#include <hip/hip_bf16.h>
#include <type_traits>

using bf16 = __hip_bfloat16;

typedef __bf16 bf16x8 __attribute__((ext_vector_type(8)));
typedef unsigned short u16x8 __attribute__((ext_vector_type(8)));
typedef float f32x4 __attribute__((ext_vector_type(4)));

constexpr int Bdim = 8, Sdim = 2048, Idim = 1024, Hdim = 4096, Odim = 1024;
constexpr int CH = 64;              // scan chunks per sequence
constexpr int CL = Sdim / CH;       // 32 steps per chunk

#define EP_SIGMOID 0
#define EP_RELU    1
#define EP_BIAS    2

__device__ __forceinline__ void async16(void* lds, const void* g) {
    __builtin_amdgcn_global_load_lds(
        (const __attribute__((address_space(1))) unsigned int*)g,
        (__attribute__((address_space(3))) unsigned int*)lds,
        16, 0, 0);
}

// f32 -> bf16 convert; n multiple of 1024; 4 elems/thread
__global__ __launch_bounds__(256) void cvt_f32_bf16(const float* __restrict__ in,
                                                    bf16* __restrict__ out, int n) {
    const int i = (blockIdx.x * 256 + threadIdx.x) * 4;
    if (i >= n) return;
    const float4 v = *(const float4*)(in + i);
    union { unsigned short us[4]; unsigned long long u64; } r;
    r.us[0] = __bfloat16_as_ushort(__float2bfloat16(v.x));
    r.us[1] = __bfloat16_as_ushort(__float2bfloat16(v.y));
    r.us[2] = __bfloat16_as_ushort(__float2bfloat16(v.z));
    r.us[3] = __bfloat16_as_ushort(__float2bfloat16(v.w));
    *(unsigned long long*)(out + i) = r.u64;
}

// load 8 consecutive elements as bf16 (f32 converted in-register)
__device__ __forceinline__ u16x8 load8(const float* p) {
    const float4 v0 = *(const float4*)p;
    const float4 v1 = *(const float4*)(p + 4);
    u16x8 r;
    r[0] = __bfloat16_as_ushort(__float2bfloat16(v0.x));
    r[1] = __bfloat16_as_ushort(__float2bfloat16(v0.y));
    r[2] = __bfloat16_as_ushort(__float2bfloat16(v0.z));
    r[3] = __bfloat16_as_ushort(__float2bfloat16(v0.w));
    r[4] = __bfloat16_as_ushort(__float2bfloat16(v1.x));
    r[5] = __bfloat16_as_ushort(__float2bfloat16(v1.y));
    r[6] = __bfloat16_as_ushort(__float2bfloat16(v1.z));
    r[7] = __bfloat16_as_ushort(__float2bfloat16(v1.w));
    return r;
}
__device__ __forceinline__ u16x8 load8(const bf16* p) { return *(const u16x8*)p; }

__device__ __forceinline__ float toF(float v) { return v; }
__device__ __forceinline__ float toF(bf16 v)  { return __bfloat162float(v); }

// C[m,n] = sum_k A[m,k]*B[n,k] (B row-major [N,K] == B^T). f32 bias.
// Compile-time N,K (VALUBusy 36->9% measured r7). 128x128 tile, BK=32,
// 256 thr, 2x2 waves, 4x4 MFMA. GRP=8 group swizzle (FETCH 270->66MB
// measured r6): group = 8 m-tiles x all n-tiles -> A-strips + B panel
// stay hot in L2/L3 across the group.
template <int MODE, int N, int K, typename TA, typename TB, typename TO>
__global__ __launch_bounds__(256) void gemm_bt(const TA* __restrict__ A,
                                               const TB* __restrict__ Bm,
                                               const float* __restrict__ bias,
                                               TO* __restrict__ outp,
                                               int Mt) {
    __shared__ __align__(16) unsigned short Alds[128 * 32];
    __shared__ __align__(16) unsigned short Blds[128 * 32];

    const int tid  = threadIdx.x;
    const int lane = tid & 63;
    const int wave = tid >> 6;
    const int wr = wave >> 1, wc = wave & 1;
    const int quad = lane >> 4, l15 = lane & 15;

    // ---- GRP=8 group-swizzled rasterization (r6-proven) ----
    constexpr int Nt = N >> 7;
    constexpr int GRP = 8;
    constexpr int gsz = GRP * Nt;       // compile-time -> shifts
    const int g   = blockIdx.x / gsz;
    const int rem = blockIdx.x - g * gsz;
    const int mbase = g * GRP;
    int msz = Mt - mbase; if (msz > GRP) msz = GRP;   // M multiple of 1024 -> always 8
    const int m_idx = mbase + rem % msz;
    const int n_idx = rem / msz;
    const int m0 = m_idx * 128;
    const int n0 = n_idx * 128;

    // staging: thread t covers (row = t>>2 [+64], k-chunk = (t&3)*8)
    const int srow = tid >> 2;
    const int scol = (tid & 3) * 8;
    const TA* ag0 = A  + (size_t)(m0 + srow) * K + scol;
    const TA* ag1 = ag0 + (size_t)64 * K;
    const TB* bg0 = Bm + (size_t)(n0 + srow) * K + scol;
    const TB* bg1 = bg0 + (size_t)64 * K;
    unsigned short* al0 = Alds + tid * 8;
    unsigned short* al1 = al0 + 2048;
    unsigned short* bl0 = Blds + tid * 8;
    unsigned short* bl1 = bl0 + 2048;

    f32x4 acc[4][4];
#pragma unroll
    for (int i = 0; i < 4; ++i)
#pragma unroll
        for (int j = 0; j < 4; ++j) acc[i][j] = {0.f, 0.f, 0.f, 0.f};

    constexpr bool FAST = std::is_same_v<TA, bf16> && std::is_same_v<TB, bf16>;

#pragma unroll 8
    for (int k0 = 0; k0 < K; k0 += 32) {
        if constexpr (FAST) {
            async16(al0, ag0); async16(al1, ag1);
            async16(bl0, bg0); async16(bl1, bg1);
        } else {
            const u16x8 a0 = load8(ag0), a1 = load8(ag1);
            const u16x8 b0 = load8(bg0), b1 = load8(bg1);
            *(u16x8*)al0 = a0; *(u16x8*)al1 = a1;
            *(u16x8*)bl0 = b0; *(u16x8*)bl1 = b1;
        }
        ag0 += 32; ag1 += 32; bg0 += 32; bg1 += 32;
        __syncthreads();   // tiles ready (drains vmcnt for async path)

        bf16x8 af[4], bfv[4];
#pragma unroll
        for (int mi = 0; mi < 4; ++mi) {
            const u16x8 t = *(const u16x8*)(Alds + (wr * 64 + mi * 16 + l15) * 32 + quad * 8);
            af[mi] = __builtin_bit_cast(bf16x8, t);
        }
#pragma unroll
        for (int ni = 0; ni < 4; ++ni) {
            const u16x8 t = *(const u16x8*)(Blds + (wc * 64 + ni * 16 + l15) * 32 + quad * 8);
            bfv[ni] = __builtin_bit_cast(bf16x8, t);
        }
#pragma unroll
        for (int mi = 0; mi < 4; ++mi)
#pragma unroll
            for (int ni = 0; ni < 4; ++ni)
                acc[mi][ni] = __builtin_amdgcn_mfma_f32_16x16x32_bf16(af[mi], bfv[ni], acc[mi][ni], 0, 0, 0);
        __syncthreads();   // protect LDS for next stage
    }

    // D: row = quad*4 + reg, col = l15 (verified m89/m91 mapping)
#pragma unroll
    for (int ni = 0; ni < 4; ++ni) {
        const int ncol = n0 + wc * 64 + ni * 16 + l15;
        const float bv = bias[ncol];
#pragma unroll
        for (int mi = 0; mi < 4; ++mi) {
            const int mrow = m0 + wr * 64 + mi * 16 + quad * 4;
#pragma unroll
            for (int r = 0; r < 4; ++r) {
                float v = acc[mi][ni][r] + bv;
                if constexpr (MODE == EP_SIGMOID) v = 1.f / (1.f + __expf(-v));
                if constexpr (MODE == EP_RELU)    v = v > 0.f ? v : 0.f;
                if constexpr (std::is_same_v<TO, bf16>)
                    outp[(size_t)(mrow + r) * N + ncol] = __float2bfloat16(v);
                else
                    outp[(size_t)(mrow + r) * N + ncol] = v;
            }
        }
    }
}

// phase 1: per-chunk affine coefficients  buf_out = P*buf_in + Q
template <typename XT>
__global__ __launch_bounds__(256) void scan_p1(const XT* __restrict__ x,
                                               const bf16* __restrict__ decay,
                                               float* __restrict__ P,
                                               float* __restrict__ Q) {
    const int tid = threadIdx.x;
    const int blk = blockIdx.x;          // (b*CH + c)*4 + itile
    const int itile = blk & 3;
    const int bc = blk >> 2;
    const int c = bc & (CH - 1);
    const int b = bc >> 6;
    const int i = itile * 256 + tid;
    size_t idx = ((size_t)(b * Sdim + c * CL)) * Idim + i;
    float p = 1.f, q = 0.f;
#pragma unroll 4
    for (int j = 0; j < CL; ++j) {
        const float d = __bfloat162float(decay[idx]);
        const float xx = toF(x[idx]);
        q = q * d + (1.f - d) * xx;
        p *= d;
        idx += Idim;
    }
    P[(size_t)bc * Idim + i] = p;
    Q[(size_t)bc * Idim + i] = q;
}

// phase 2: sequential combine across chunks (tiny)
__global__ __launch_bounds__(256) void scan_p2(const float* __restrict__ P,
                                               const float* __restrict__ Q,
                                               float* __restrict__ buf0,
                                               int G) {
    const int g = blockIdx.x * 256 + threadIdx.x;
    const int b = g >> 10;
    const int i = g & (Idim - 1);
    if (b >= G) return;
    float buf = 0.f;
    for (int c = 0; c < CH; ++c) {
        const size_t o = ((size_t)(b * CH + c)) * Idim + i;
        buf0[o] = buf;
        buf = P[o] * buf + Q[o];
    }
}

// phase 3: replay with correct init, write combined = x*d + buf (bf16)
template <typename XT>
__global__ __launch_bounds__(256) void scan_p3(const XT* __restrict__ x,
                                               const bf16* __restrict__ decay,
                                               const float* __restrict__ buf0,
                                               bf16* __restrict__ comb) {
    const int tid = threadIdx.x;
    const int blk = blockIdx.x;
    const int itile = blk & 3;
    const int bc = blk >> 2;
    const int c = bc & (CH - 1);
    const int b = bc >> 6;
    const int i = itile * 256 + tid;
    size_t idx = ((size_t)(b * Sdim + c * CL)) * Idim + i;
    float buf = buf0[(size_t)bc * Idim + i];
#pragma unroll 4
    for (int j = 0; j < CL; ++j) {
        const float d = __bfloat162float(decay[idx]);
        const float xx = toF(x[idx]);
        buf = buf * d + (1.f - d) * xx;
        comb[idx] = __float2bfloat16(xx * d + buf);
        idx += Idim;
    }
}

extern "C" void kernel_launch(void* const* d_in, const int* in_sizes, int n_in,
                              void* d_out, int out_size, void* d_ws, size_t ws_size,
                              hipStream_t stream) {
    const float* x  = (const float*)d_in[0];
    const float* W1 = (const float*)d_in[1];
    const float* b1 = (const float*)d_in[2];
    const float* W2 = (const float*)d_in[3];
    const float* b2 = (const float*)d_in[4];
    const float* Wg = (const float*)d_in[5];
    const float* bg = (const float*)d_in[6];
    float* out = (float*)d_out;                       // output is f32

    const dim3 blk(256);

    const size_t nW1 = (size_t)Hdim * Idim;
    const size_t nW2 = (size_t)Odim * Hdim;
    const size_t nWg = (size_t)Idim * Idim;
    const size_t wCopies = (nW1 + nW2 + nWg) * 2;     // 18.9 MB

    const size_t xbB   = (size_t)Sdim * Idim * 2;     // per-batch bf16 x: 4 MB
    const size_t dB    = xbB;                         // decay: 4 MB
    const size_t cmbB  = xbB;                         // comb: 4 MB
    const size_t pB    = (size_t)CH * Idim * 4;       // 256 KB
    const size_t perBatch = xbB + dB + cmbB + 3 * pB; // 12.75 MB

    int G = 0;                                         // 0 = fallback mode
    if (ws_size >= wCopies + 8 * perBatch) G = 8;
    else if (ws_size >= wCopies + 4 * perBatch) G = 4;
    else if (ws_size >= wCopies + 2 * perBatch) G = 2;
    else if (ws_size >= wCopies + 1 * perBatch) G = 1;

    if (G > 0) {
        // ---------- fast path: bf16 copies + async16 GEMMs ----------
        char* p = (char*)d_ws;
        bf16* W1b = (bf16*)p;  p += nW1 * 2;
        bf16* W2b = (bf16*)p;  p += nW2 * 2;
        bf16* Wgb = (bf16*)p;  p += nWg * 2;
        bf16*  xb   = (bf16*)p;
        bf16*  decay= (bf16*)(p + (size_t)G * xbB);
        bf16*  comb = (bf16*)(p + (size_t)G * (xbB + dB));
        float* P    = (float*)(p + (size_t)G * (xbB + dB + cmbB));
        float* Q    = (float*)(p + (size_t)G * (xbB + dB + cmbB + pB));
        float* buf0 = (float*)(p + (size_t)G * (xbB + dB + cmbB + 2 * pB));
        bf16*  hid  = xb;                 // reuses xb+decay (G*8MB) after scan
        const int chunk_rows = G * 1024;  // hid = chunk_rows*Hdim*2 = G*8MB

        cvt_f32_bf16<<<(int)(nW1 / 1024), blk, 0, stream>>>(W1, W1b, (int)nW1);
        cvt_f32_bf16<<<(int)(nW2 / 1024), blk, 0, stream>>>(W2, W2b, (int)nW2);
        cvt_f32_bf16<<<(int)(nWg / 1024), blk, 0, stream>>>(Wg, Wgb, (int)nWg);

        for (int b0 = 0; b0 < Bdim; b0 += G) {
            const float* xg = x + (size_t)b0 * Sdim * Idim;
            const int rowsG = G * Sdim;
            const int nXg = rowsG * Idim;

            cvt_f32_bf16<<<nXg / 1024, blk, 0, stream>>>(xg, xb, nXg);

            gemm_bt<EP_SIGMOID, Idim, Idim, bf16, bf16, bf16>
                <<<(Idim / 128) * (rowsG / 128), blk, 0, stream>>>(
                    xb, Wgb, bg, decay, rowsG / 128);

            scan_p1<bf16><<<G * CH * (Idim / 256), blk, 0, stream>>>(xb, decay, P, Q);
            scan_p2<<<G * Idim / 256, blk, 0, stream>>>(P, Q, buf0, G);
            scan_p3<bf16><<<G * CH * (Idim / 256), blk, 0, stream>>>(xb, decay, buf0, comb);

            for (int r0 = 0; r0 < rowsG; r0 += chunk_rows) {
                const int rows = (rowsG - r0 < chunk_rows) ? rowsG - r0 : chunk_rows;
                gemm_bt<EP_RELU, Hdim, Idim, bf16, bf16, bf16>
                    <<<(Hdim / 128) * (rows / 128), blk, 0, stream>>>(
                        comb + (size_t)r0 * Idim, W1b, b1, hid, rows / 128);
                gemm_bt<EP_BIAS, Odim, Hdim, bf16, bf16, float>
                    <<<(Odim / 128) * (rows / 128), blk, 0, stream>>>(
                        hid, W2b, b2, out + (size_t)(b0 * Sdim + r0) * Odim, rows / 128);
            }
        }
    } else {
        // ---------- fallback: no copies, in-register f32->bf16 ----------
        char* p = (char*)d_ws;
        bf16*  decay= (bf16*)p;
        bf16*  comb = (bf16*)(p + dB);
        float* P    = (float*)(p + dB + cmbB);
        float* Q    = (float*)(p + dB + cmbB + pB);
        float* buf0 = (float*)(p + dB + cmbB + 2 * pB);
        char*  hp   = p + dB + cmbB + 3 * pB;
        size_t rem  = (ws_size > (size_t)(hp - (char*)d_ws))
                        ? ws_size - (size_t)(hp - (char*)d_ws) : 0;
        int chunk_rows = (int)((rem / ((size_t)Hdim * 2)) / 128) * 128;
        if (chunk_rows < 128) chunk_rows = 128;
        if (chunk_rows > Sdim) chunk_rows = Sdim;
        bf16* hid = (bf16*)hp;

        for (int b0 = 0; b0 < Bdim; ++b0) {
            const float* xg = x + (size_t)b0 * Sdim * Idim;

            gemm_bt<EP_SIGMOID, Idim, Idim, float, float, bf16>
                <<<(Idim / 128) * (Sdim / 128), blk, 0, stream>>>(
                    xg, Wg, bg, decay, Sdim / 128);

            scan_p1<float><<<CH * (Idim / 256), blk, 0, stream>>>(xg, decay, P, Q);
            scan_p2<<<Idim / 256, blk, 0, stream>>>(P, Q, buf0, 1);
            scan_p3<float><<<CH * (Idim / 256), blk, 0, stream>>>(xg, decay, buf0, comb);

            for (int r0 = 0; r0 < Sdim; r0 += chunk_rows) {
                const int rows = (Sdim - r0 < chunk_rows) ? Sdim - r0 : chunk_rows;
                gemm_bt<EP_RELU, Hdim, Idim, bf16, float, bf16>
                    <<<(Hdim / 128) * (rows / 128), blk, 0, stream>>>(
                        comb + (size_t)r0 * Idim, W1, b1, hid, rows / 128);
                gemm_bt<EP_BIAS, Odim, Hdim, bf16, float, float>
                    <<<(Odim / 128) * (rows / 128), blk, 0, stream>>>(
                        hid, W2, b2, out + (size_t)(b0 * Sdim + r0) * Odim, rows / 128);
            }
        }
    }
}